// Round 1
// baseline (21779.962 us; speedup 1.0000x reference)
//
#include <hip/hip_runtime.h>
#include <cstddef>
#include <cstdint>

// Problem constants
#define B_ 64
#define T_ 128
#define N_ 64
#define D_ 64
#define Q_ 5
#define E_ 8
#define P_ 768
#define F_ 129    // 2D+1 combined feature dim
#define FP_ 136   // F padded to 17*8 (fp16 rows, 16B-aligned, zero pad)
#define H_ 128    // MLP hidden (2D)
#define CT_ 66    // combT row pad (columns = nodes), even for half2 loads

typedef _Float16 f16;
typedef _Float16 f16x2 __attribute__((ext_vector_type(2)));
typedef _Float16 f16x8 __attribute__((ext_vector_type(8)));

union V8 { f16x8 v; f16x2 p[4]; };

__device__ __forceinline__ float dot2f(f16x2 a, f16x2 b, float c) {
#if __has_builtin(__builtin_amdgcn_fdot2)
  return __builtin_amdgcn_fdot2(a, b, c, false);
#else
  return c + (float)a[0] * (float)b[0] + (float)a[1] * (float)b[1];
#endif
}

// ---------------------------------------------------------------------------
// K1: per-node MLPs -> qv (N,Q) and row-normalized ne (N,E). One block per n.
// ---------------------------------------------------------------------------
__global__ void k_mlps(const float* __restrict__ vpr,
                       const float* __restrict__ Wf1, const float* __restrict__ bf1,
                       const float* __restrict__ Wf2, const float* __restrict__ bf2,
                       const float* __restrict__ Wg1, const float* __restrict__ bg1,
                       const float* __restrict__ Wg2, const float* __restrict__ bg2,
                       float* __restrict__ qv, float* __restrict__ neb) {
  int n = blockIdx.x;
  int tid = threadIdx.x;  // 256
  __shared__ float v[P_];
  __shared__ float hid[H_];
  __shared__ float tmp[E_];

  for (int i = tid; i < P_; i += 256) v[i] = vpr[n * P_ + i];
  __syncthreads();

  // f-MLP hidden
  for (int j = tid; j < H_; j += 256) {
    float a = bf1[j];
#pragma unroll 8
    for (int i = 0; i < P_; ++i) a += v[i] * Wf1[i * H_ + j];
    hid[j] = fmaxf(a, 0.f);
  }
  __syncthreads();
  if (tid < Q_) {
    float a = bf2[tid];
    for (int j = 0; j < H_; ++j) a += hid[j] * Wf2[j * Q_ + tid];
    qv[n * Q_ + tid] = a;
  }
  __syncthreads();

  // g-MLP hidden (reuse hid)
  for (int j = tid; j < H_; j += 256) {
    float a = bg1[j];
#pragma unroll 8
    for (int i = 0; i < P_; ++i) a += v[i] * Wg1[i * H_ + j];
    hid[j] = fmaxf(a, 0.f);
  }
  __syncthreads();
  if (tid < E_) {
    float a = bg2[tid];
    for (int j = 0; j < H_; ++j) a += hid[j] * Wg2[j * E_ + tid];
    tmp[tid] = a;
  }
  __syncthreads();
  if (tid == 0) {
    float s = 0.f;
    for (int e = 0; e < E_; ++e) s += tmp[e] * tmp[e];
    float r = 1.f / sqrtf(s);
    for (int e = 0; e < E_; ++e) neb[n * E_ + e] = tmp[e] * r;
  }
}

// ---------------------------------------------------------------------------
// K2: adj row softmax (N,N) + per-node gate biases. One block (64 thr) per n.
// ---------------------------------------------------------------------------
__global__ void k_adj_bias(const float* __restrict__ neb, const float* __restrict__ qv,
                           const float* __restrict__ br, const float* __restrict__ bu,
                           const float* __restrict__ bc,
                           float* __restrict__ adj, float* __restrict__ brn,
                           float* __restrict__ bun, float* __restrict__ bcn) {
  int n = blockIdx.x;
  int j = threadIdx.x;  // 64 = one wave
  float s = 0.f;
#pragma unroll
  for (int e = 0; e < E_; ++e) s += neb[n * E_ + e] * neb[j * E_ + e];
  float m = s;
  for (int off = 32; off; off >>= 1) m = fmaxf(m, __shfl_xor(m, off));
  float ex = expf(s - m);
  float sum = ex;
  for (int off = 32; off; off >>= 1) sum += __shfl_xor(sum, off);
  adj[n * N_ + j] = ex / sum;

  float pr = 0.f, pu = 0.f, pc = 0.f;
#pragma unroll
  for (int q = 0; q < Q_; ++q) {
    float qvv = qv[n * Q_ + q];
    pr += qvv * br[q * D_ + j];
    pu += qvv * bu[q * D_ + j];
    pc += qvv * bc[q * D_ + j];
  }
  brn[n * D_ + j] = pr;
  bun[n * D_ + j] = pu;
  bcn[n * D_ + j] = pc;
}

// ---------------------------------------------------------------------------
// K3: per-node fp16 weights, layout WNT[g][n][o][fp<FP_] = sum_q qv[n,q]*W[q][fp][o]
//     (zero pad fp in [129,136) so dot2 over pads is a no-op). 192 blocks.
// ---------------------------------------------------------------------------
__global__ void k_wn(const float* __restrict__ qv,
                     const float* __restrict__ Wr, const float* __restrict__ Wu,
                     const float* __restrict__ Wc, f16* __restrict__ WNT) {
  int g = blockIdx.x >> 6;
  int n = blockIdx.x & 63;
  int tid = threadIdx.x;  // 256
  const float* W = (g == 0) ? Wr : ((g == 1) ? Wu : Wc);
  float qs[Q_];
#pragma unroll
  for (int q = 0; q < Q_; ++q) qs[q] = qv[n * Q_ + q];
  for (int idx = tid; idx < D_ * FP_; idx += 256) {
    int o = idx / FP_;
    int fp = idx - o * FP_;
    float a = 0.f;
    if (fp < F_) {
#pragma unroll
      for (int q = 0; q < Q_; ++q) a += qs[q] * W[(q * F_ + fp) * D_ + o];
    }
    WNT[((size_t)(g * N_ + n) * D_ + o) * FP_ + fp] = (f16)a;
  }
}

// ---------------------------------------------------------------------------
// K4: var_total[b][n] = sum_t mask
// ---------------------------------------------------------------------------
__global__ void k_vt(const float* __restrict__ mask, float* __restrict__ vt) {
  int b = blockIdx.x;
  int n = threadIdx.x;  // 64
  float s = 0.f;
  for (int t = 0; t < T_; ++t) s += mask[(b * T_ + t) * N_ + n];
  vt[b * N_ + n] = s;
}

// ---------------------------------------------------------------------------
// SEQ: the recurrence. One block (512 thr) per batch. fp16 operands via
// v_dot2_f32_f16, fp32 h-state in registers (8 per thread).
// ---------------------------------------------------------------------------
__launch_bounds__(512, 1)
__global__ void k_seq(const float* __restrict__ obs, const float* __restrict__ mask,
                      const int* __restrict__ lengths, const float* __restrict__ ai,
                      const float* __restrict__ rarw, const float* __restrict__ adjG,
                      const float* __restrict__ brn, const float* __restrict__ bun,
                      const float* __restrict__ bcn, const float* __restrict__ vt,
                      const f16* __restrict__ WNT, float* __restrict__ out) {
  int b = blockIdx.x;
  int tid = threadIdx.x;

  // LDS (static, 61 KB total)
  __shared__ __align__(16) f16 combT[130 * CT_];   // [feature f][node j]: rows 0..63=x, 64=rs, 65..128=h(t-1)
  __shared__ __align__(16) f16 comb2R[N_ * FP_];   // [node n][f]: x, rs, h_r ; pads zero
  __shared__ __align__(16) f16 msg16[N_ * FP_];    // [node n][f] ; pads zero
  __shared__ __align__(16) f16 A16[N_ * CT_];      // [i][j]
  __shared__ float rsS[N_];
  __shared__ float mS[N_];
  __shared__ float vtS[N_];

  // zero-init LDS (ws/out are poisoned; pads must be 0)
  for (int i = tid; i < 130 * CT_; i += 512) combT[i] = (f16)0.f;
  for (int i = tid; i < N_ * FP_; i += 512) { comb2R[i] = (f16)0.f; msg16[i] = (f16)0.f; }
  for (int i = tid; i < N_ * CT_; i += 512) A16[i] = (f16)0.f;
  if (tid < N_) vtS[tid] = vt[b * N_ + tid];

  // fixed thread roles
  const int ig = tid >> 5, fg = tid & 31;        // phase3: i-block 4, f strided by 32
  const int i0 = ig * 4;
  const int n4 = tid >> 3, og4 = tid & 7;        // phases 4-6: node n4, 8 outputs at og4*8
  const int o0 = og4 * 8;

  float hreg[8];
  float bRv[8], bUv[8], bCv[8];
#pragma unroll
  for (int k = 0; k < 8; ++k) {
    hreg[k] = 0.f;
    bRv[k] = brn[n4 * D_ + o0 + k];
    bUv[k] = bun[n4 * D_ + o0 + k];
    bCv[k] = bcn[n4 * D_ + o0 + k];
  }
  const f16* wr0 = WNT + ((size_t)n4 * D_ + o0) * FP_;
  const f16* wu0 = wr0 + (size_t)N_ * D_ * FP_;
  const f16* wc0 = wr0 + (size_t)2 * N_ * D_ * FP_;

  int lenm1 = lengths[b] - 1;
  __syncthreads();

  for (int t = 0; t < T_; ++t) {
    // ---- phase1: rs/mask + x staging (both fp16 copies) ----
    if (tid < N_) {
      float mv = mask[(b * T_ + t) * N_ + tid];
      float aiv = ai[(b * T_ + t) * N_ + tid];
      float rsv = 0.5f * tanhf(aiv / (vtS[tid] + 1.f));
      mS[tid] = mv;
      rsS[tid] = rsv;
      comb2R[tid * FP_ + 64] = (f16)rsv;
      combT[64 * CT_ + tid] = (f16)rsv;
    }
    {
      const float* xb = obs + (size_t)(b * T_ + t) * (N_ * D_);
      for (int idx = tid; idx < N_ * D_; idx += 512) {
        float v = xb[idx];
        int nn = idx >> 6, dd = idx & 63;
        comb2R[nn * FP_ + dd] = (f16)v;
        combT[dd * CT_ + nn] = (f16)v;
      }
    }
    __syncthreads();

    // ---- phase2: build A (fp16), diag exactly 1 ----
    for (int idx = tid; idx < N_ * N_ / 2; idx += 512) {
      int i = idx >> 5, jp = idx & 31;
      int j0 = 2 * jp;
      float2 ad = *(const float2*)&adjG[i * N_ + j0];
      float2 rw = *(const float2*)&rarw[i * N_ + j0];
      float ri = rsS[i], mi = mS[i];
      float a0 = ad.x * (1.f - rw.x * fabsf(ri - rsS[j0])) * mi * mS[j0];
      float a1 = ad.y * (1.f - rw.y * fabsf(ri - rsS[j0 + 1])) * mi * mS[j0 + 1];
      if (i == j0) a0 = 1.f;
      if (i == j0 + 1) a1 = 1.f;
      f16x2 av = {(f16)a0, (f16)a1};
      *(f16x2*)&A16[i * CT_ + j0] = av;
    }
    __syncthreads();

    // ---- phase3: msg = A @ combined (dot2 over node pairs) ----
    {
      float acc[4][4] = {{0.f}};
      float accE[4] = {0.f, 0.f, 0.f, 0.f};
      for (int jp = 0; jp < 32; ++jp) {
        f16x2 a2[4];
#pragma unroll
        for (int ii = 0; ii < 4; ++ii)
          a2[ii] = *(const f16x2*)&A16[(i0 + ii) * CT_ + 2 * jp];
#pragma unroll
        for (int kk = 0; kk < 4; ++kk) {
          f16x2 c2 = *(const f16x2*)&combT[(fg + 32 * kk) * CT_ + 2 * jp];
#pragma unroll
          for (int ii = 0; ii < 4; ++ii) acc[ii][kk] = dot2f(a2[ii], c2, acc[ii][kk]);
        }
        if (fg == 0) {
          f16x2 ce = *(const f16x2*)&combT[128 * CT_ + 2 * jp];
#pragma unroll
          for (int ii = 0; ii < 4; ++ii) accE[ii] = dot2f(a2[ii], ce, accE[ii]);
        }
      }
#pragma unroll
      for (int ii = 0; ii < 4; ++ii) {
#pragma unroll
        for (int kk = 0; kk < 4; ++kk)
          msg16[(i0 + ii) * FP_ + fg + 32 * kk] = (f16)acc[ii][kk];
        if (fg == 0) msg16[(i0 + ii) * FP_ + 128] = (f16)accE[ii];
      }
    }
    __syncthreads();

    // ---- phase4: r,u gates (stream fp16 per-node weights from L2) ----
    bool upd = mS[n4] > 0.f;
    float ureg[8], hrreg[8];
    {
      const f16x8* m8p = (const f16x8*)(msg16 + n4 * FP_);
#pragma unroll
      for (int k = 0; k < 8; ++k) {
        float aR = bRv[k], aU = bUv[k];
        const f16x8* wr8 = (const f16x8*)(wr0 + (size_t)k * FP_);
        const f16x8* wu8 = (const f16x8*)(wu0 + (size_t)k * FP_);
#pragma unroll
        for (int p = 0; p < 17; ++p) {
          V8 m, w, x;
          m.v = m8p[p]; w.v = wr8[p]; x.v = wu8[p];
#pragma unroll
          for (int q2 = 0; q2 < 4; ++q2) {
            aR = dot2f(m.p[q2], w.p[q2], aR);
            aU = dot2f(m.p[q2], x.p[q2], aU);
          }
        }
        float r = 1.f / (1.f + expf(-aR));
        float u = 1.f / (1.f + expf(-aU));
        float hold = hreg[k];
        float hr = upd ? r * hold : hold;
        ureg[k] = u;
        hrreg[k] = hr;
        comb2R[n4 * FP_ + 65 + o0 + k] = (f16)hr;
      }
    }
    __syncthreads();

    // ---- phase5+6: candidate + h update + output ----
    {
      float pc[8];
      const f16x8* c8p = (const f16x8*)(comb2R + n4 * FP_);
#pragma unroll
      for (int k = 0; k < 8; ++k) {
        float aC = bCv[k];
        const f16x8* wc8 = (const f16x8*)(wc0 + (size_t)k * FP_);
#pragma unroll
        for (int p = 0; p < 17; ++p) {
          V8 c, w;
          c.v = c8p[p]; w.v = wc8[p];
#pragma unroll
          for (int q2 = 0; q2 < 4; ++q2) aC = dot2f(c.p[q2], w.p[q2], aC);
        }
        pc[k] = aC;
      }
#pragma unroll
      for (int k = 0; k < 8; ++k) {
        float cand = tanhf(pc[k]);
        float hn = upd ? (1.f - ureg[k]) * hrreg[k] + ureg[k] * cand : hreg[k];
        hreg[k] = hn;
        combT[(65 + o0 + k) * CT_ + n4] = (f16)hn;
        if (t == lenm1) out[((size_t)b * N_ + n4) * D_ + o0 + k] = hn;
      }
    }
    __syncthreads();
  }
}

// ---------------------------------------------------------------------------
extern "C" void kernel_launch(void* const* d_in, const int* in_sizes, int n_in,
                              void* d_out, int out_size, void* d_ws, size_t ws_size,
                              hipStream_t stream) {
  const float* obs  = (const float*)d_in[0];
  const float* mask = (const float*)d_in[1];
  const int*   lens = (const int*)d_in[2];
  const float* ai   = (const float*)d_in[3];
  const float* vpr  = (const float*)d_in[4];
  const float* rarw = (const float*)d_in[5];
  const float* Wf1 = (const float*)d_in[6],  *bf1 = (const float*)d_in[7];
  const float* Wf2 = (const float*)d_in[8],  *bf2 = (const float*)d_in[9];
  const float* Wg1 = (const float*)d_in[10], *bg1 = (const float*)d_in[11];
  const float* Wg2 = (const float*)d_in[12], *bg2 = (const float*)d_in[13];
  const float* Wu = (const float*)d_in[14], *bu = (const float*)d_in[15];
  const float* Wr = (const float*)d_in[16], *br = (const float*)d_in[17];
  const float* Wc = (const float*)d_in[18], *bc = (const float*)d_in[19];

  // workspace carve (256B aligned); total ~3.5 MB
  char* p = (char*)d_ws;
  auto carve = [&](size_t bytes) {
    char* r = p;
    p += (bytes + 255) & ~(size_t)255;
    return r;
  };
  float* qv  = (float*)carve(N_ * Q_ * 4);
  float* neb = (float*)carve(N_ * E_ * 4);
  float* adj = (float*)carve(N_ * N_ * 4);
  float* brn = (float*)carve(N_ * D_ * 4);
  float* bun = (float*)carve(N_ * D_ * 4);
  float* bcn = (float*)carve(N_ * D_ * 4);
  float* vt  = (float*)carve(B_ * N_ * 4);
  f16* WNT   = (f16*)carve((size_t)3 * N_ * D_ * FP_ * 2);

  k_mlps<<<N_, 256, 0, stream>>>(vpr, Wf1, bf1, Wf2, bf2, Wg1, bg1, Wg2, bg2, qv, neb);
  k_adj_bias<<<N_, 64, 0, stream>>>(neb, qv, br, bu, bc, adj, brn, bun, bcn);
  k_wn<<<3 * N_, 256, 0, stream>>>(qv, Wr, Wu, Wc, WNT);
  k_vt<<<B_, 64, 0, stream>>>(mask, vt);
  k_seq<<<B_, 512, 0, stream>>>(obs, mask, lens, ai, rarw, adj, brn, bun, bcn, vt, WNT,
                                (float*)d_out);
}

// Round 2
// 2152.779 us; speedup vs baseline: 10.1171x; 10.1171x over previous
//
#include <hip/hip_runtime.h>
#include <cstddef>
#include <cstdint>

// Problem constants
#define B_ 64
#define T_ 128
#define N_ 64
#define D_ 64
#define Q_ 5
#define E_ 8
#define P_ 768
#define H_ 128

typedef _Float16 f16;
typedef _Float16 f16x2 __attribute__((ext_vector_type(2)));
typedef _Float16 f16x4 __attribute__((ext_vector_type(4)));
typedef _Float16 f16x8 __attribute__((ext_vector_type(8)));
typedef float f32x4 __attribute__((ext_vector_type(4)));

// ---------------------------------------------------------------------------
// K1: per-node MLPs -> qv (N,Q) and row-normalized ne (N,E). One block per n.
// ---------------------------------------------------------------------------
__global__ void k_mlps(const float* __restrict__ vpr,
                       const float* __restrict__ Wf1, const float* __restrict__ bf1,
                       const float* __restrict__ Wf2, const float* __restrict__ bf2,
                       const float* __restrict__ Wg1, const float* __restrict__ bg1,
                       const float* __restrict__ Wg2, const float* __restrict__ bg2,
                       float* __restrict__ qv, float* __restrict__ neb) {
  int n = blockIdx.x;
  int tid = threadIdx.x;  // 256
  __shared__ float v[P_];
  __shared__ float hid[H_];
  __shared__ float tmp[E_];

  for (int i = tid; i < P_; i += 256) v[i] = vpr[n * P_ + i];
  __syncthreads();

  for (int j = tid; j < H_; j += 256) {
    float a = bf1[j];
#pragma unroll 8
    for (int i = 0; i < P_; ++i) a += v[i] * Wf1[i * H_ + j];
    hid[j] = fmaxf(a, 0.f);
  }
  __syncthreads();
  if (tid < Q_) {
    float a = bf2[tid];
    for (int j = 0; j < H_; ++j) a += hid[j] * Wf2[j * Q_ + tid];
    qv[n * Q_ + tid] = a;
  }
  __syncthreads();

  for (int j = tid; j < H_; j += 256) {
    float a = bg1[j];
#pragma unroll 8
    for (int i = 0; i < P_; ++i) a += v[i] * Wg1[i * H_ + j];
    hid[j] = fmaxf(a, 0.f);
  }
  __syncthreads();
  if (tid < E_) {
    float a = bg2[tid];
    for (int j = 0; j < H_; ++j) a += hid[j] * Wg2[j * E_ + tid];
    tmp[tid] = a;
  }
  __syncthreads();
  if (tid == 0) {
    float s = 0.f;
    for (int e = 0; e < E_; ++e) s += tmp[e] * tmp[e];
    float r = 1.f / sqrtf(s);
    for (int e = 0; e < E_; ++e) neb[n * E_ + e] = tmp[e] * r;
  }
}

// ---------------------------------------------------------------------------
// K2: adj row softmax + per-node biases + per-node rs-column weights (rank-1
// fold of feature f=64). One block (64 thr) per n.
// ---------------------------------------------------------------------------
__global__ void k_meta(const float* __restrict__ neb, const float* __restrict__ qv,
                       const float* __restrict__ br, const float* __restrict__ bu,
                       const float* __restrict__ bc,
                       const float* __restrict__ Wr, const float* __restrict__ Wu,
                       const float* __restrict__ Wc,
                       float* __restrict__ adj, float* __restrict__ brn,
                       float* __restrict__ bun, float* __restrict__ bcn,
                       float* __restrict__ WrsR, float* __restrict__ WrsU,
                       float* __restrict__ WrsC) {
  int n = blockIdx.x;
  int j = threadIdx.x;  // 64 = one wave
  float s = 0.f;
#pragma unroll
  for (int e = 0; e < E_; ++e) s += neb[n * E_ + e] * neb[j * E_ + e];
  float m = s;
  for (int off = 32; off; off >>= 1) m = fmaxf(m, __shfl_xor(m, off));
  float ex = expf(s - m);
  float sum = ex;
  for (int off = 32; off; off >>= 1) sum += __shfl_xor(sum, off);
  adj[n * N_ + j] = ex / sum;

  float pr = 0.f, pu = 0.f, pc = 0.f;
  float wr = 0.f, wu = 0.f, wc = 0.f;
#pragma unroll
  for (int q = 0; q < Q_; ++q) {
    float qq = qv[n * Q_ + q];
    pr += qq * br[q * D_ + j];
    pu += qq * bu[q * D_ + j];
    pc += qq * bc[q * D_ + j];
    wr += qq * Wr[((size_t)q * 129 + 64) * D_ + j];
    wu += qq * Wu[((size_t)q * 129 + 64) * D_ + j];
    wc += qq * Wc[((size_t)q * 129 + 64) * D_ + j];
  }
  brn[n * D_ + j] = pr;
  bun[n * D_ + j] = pu;
  bcn[n * D_ + j] = pc;
  WrsR[n * D_ + j] = wr;
  WrsU[n * D_ + j] = wu;
  WrsC[n * D_ + j] = wc;
}

// ---------------------------------------------------------------------------
// K3: pack shared gate weights into MFMA B-fragment order, fp16.
// frag id = ((g*5+q)*4+kt)*4+nt ; within frag lane l holds 8 f16:
//   B[k = 32*kt + 8*(l>>4) + e][col = 16*nt + (l&15)],  f = k + (k>=64)
// (feature order: k 0..63 = x, k 64..127 = h; f=64 (rs) folded separately)
// ---------------------------------------------------------------------------
__global__ void k_pack(const float* __restrict__ Wr, const float* __restrict__ Wu,
                       const float* __restrict__ Wc, f16* __restrict__ Wpk) {
  int bid = blockIdx.x;           // 240 = 3*5*4*4
  int nt = bid & 3;
  int kt = (bid >> 2) & 3;
  int q = (bid >> 4) % 5;
  int g = bid / 80;
  const float* W = (g == 0) ? Wr : ((g == 1) ? Wu : Wc);
  int l = threadIdx.x;            // 64
  int co = 16 * nt + (l & 15);
  f16* dst = Wpk + (size_t)bid * 512 + l * 8;
#pragma unroll
  for (int e = 0; e < 8; ++e) {
    int k = 32 * kt + 8 * (l >> 4) + e;
    int f = k + (k >= 64);
    dst[e] = (f16)W[((size_t)q * 129 + f) * D_ + co];
  }
}

// ---------------------------------------------------------------------------
// K4: var_total[b][n]
// ---------------------------------------------------------------------------
__global__ void k_vt(const float* __restrict__ mask, float* __restrict__ vt) {
  int b = blockIdx.x;
  int n = threadIdx.x;  // 64
  float s = 0.f;
  for (int t = 0; t < T_; ++t) s += mask[(b * T_ + t) * N_ + n];
  vt[b * N_ + n] = s;
}

// ---------------------------------------------------------------------------
// SEQ: one 1024-thread block per batch. MFMA 16x16x32 f16 everywhere;
// shared Q-expanded weights streamed from L2 in fragment order; fp32 h in
// registers; fp16 pre-activations staged through LDS.
// LDS budget: 65,024 B (<= 64 KiB static).
// ---------------------------------------------------------------------------
__launch_bounds__(1024, 1)
__global__ void k_seq(const float* __restrict__ obs, const float* __restrict__ mask,
                      const int* __restrict__ lengths, const float* __restrict__ ai,
                      const float* __restrict__ adjG, const float* __restrict__ rarw,
                      const float* __restrict__ brn, const float* __restrict__ bun,
                      const float* __restrict__ bcn, const float* __restrict__ WrsR,
                      const float* __restrict__ WrsU, const float* __restrict__ WrsC,
                      const float* __restrict__ qv, const float* __restrict__ vt,
                      const f16* __restrict__ Wpk, float* __restrict__ out) {
  // combT: [k-row 0..127][node j], stride 72. rows 0..63 = x(d), 64..127 = h(d)
  __shared__ __align__(16) f16 combT[128 * 72];       // 18432 B
  // Amat [i][j] stride 72 (phases P1b,P2) ALIASED with preU [n][o] stride 68 (P3->P4)
  __shared__ __align__(16) f16 AmatPre2[64 * 72];     //  9216 B
  // actA: [n][k] stride 136. P2: msg (cols 0..127). P4 overwrites cols 64..127 = h_r
  __shared__ __align__(16) f16 actA[64 * 136];        // 17408 B
  // xA: [n][d] stride 72 (A-side x for c-gate x-half)
  __shared__ __align__(16) f16 xA[64 * 72];           //  9216 B
  // pre1: preR (P3->P4) then preC (P5->P6), [n][o] stride 68
  __shared__ __align__(16) f16 pre1[64 * 68];         //  8704 B
  __shared__ __align__(16) f16 qvS[64 * 8];           //  1024 B
  __shared__ float rsS[64];
  __shared__ float mS[64];
  __shared__ float vtS[64];
  __shared__ float mrS[64];

  const int tid = threadIdx.x;
  const int b = blockIdx.x;
  const int lane = tid & 63;
  const int wv = tid >> 6;         // 16 waves
  const int lm = lane & 15;        // fragment row/col
  const int lq = lane >> 4;        // fragment quad

  // elementwise ownership: (node en, outputs eo..eo+3)
  const int en = tid >> 4;
  const int eo = (tid & 15) * 4;

  // persistent fp32 hidden state
  float h[4] = {0.f, 0.f, 0.f, 0.f};

  // per-thread constants, packed fp16 (12 VGPRs)
  f16x2 bRp[2], bUp[2], bCp[2], wRp[2], wUp[2], wCp[2];
  {
    float4 v;
    v = *(const float4*)(brn + en * D_ + eo);
    bRp[0] = f16x2{(f16)v.x, (f16)v.y}; bRp[1] = f16x2{(f16)v.z, (f16)v.w};
    v = *(const float4*)(bun + en * D_ + eo);
    bUp[0] = f16x2{(f16)v.x, (f16)v.y}; bUp[1] = f16x2{(f16)v.z, (f16)v.w};
    v = *(const float4*)(bcn + en * D_ + eo);
    bCp[0] = f16x2{(f16)v.x, (f16)v.y}; bCp[1] = f16x2{(f16)v.z, (f16)v.w};
    v = *(const float4*)(WrsR + en * D_ + eo);
    wRp[0] = f16x2{(f16)v.x, (f16)v.y}; wRp[1] = f16x2{(f16)v.z, (f16)v.w};
    v = *(const float4*)(WrsU + en * D_ + eo);
    wUp[0] = f16x2{(f16)v.x, (f16)v.y}; wUp[1] = f16x2{(f16)v.z, (f16)v.w};
    v = *(const float4*)(WrsC + en * D_ + eo);
    wCp[0] = f16x2{(f16)v.x, (f16)v.y}; wCp[1] = f16x2{(f16)v.z, (f16)v.w};
  }

  if (tid < 512) {
    int n = tid >> 3, q = tid & 7;
    qvS[n * 8 + q] = (q < Q_) ? (f16)qv[n * Q_ + q] : (f16)0.f;
  }
  if (tid < 64) vtS[tid] = vt[b * N_ + tid];
  // h(0)=0: zero combT h-rows for t=0's msg GEMM
  for (int i = tid; i < 64 * 72; i += 1024) combT[64 * 72 + i] = (f16)0.f;
  const int lenm1 = lengths[b] - 1;
  __syncthreads();

  for (int t = 0; t < T_; ++t) {
    // ---- P0: rs/mask + x staging (xA row-major, combT transposed) ----
    if (tid < 64) {
      float mv = mask[(b * T_ + t) * N_ + tid];
      float av = ai[(b * T_ + t) * N_ + tid];
      mS[tid] = mv;
      rsS[tid] = 0.5f * tanhf(av / (vtS[tid] + 1.f));
    }
    {
      float4 xv = *(const float4*)(obs + (size_t)(b * T_ + t) * (N_ * D_) + en * D_ + eo);
      f16x4 xh = {(f16)xv.x, (f16)xv.y, (f16)xv.z, (f16)xv.w};
      *(f16x4*)(xA + en * 72 + eo) = xh;
      combT[(eo + 0) * 72 + en] = xh[0];
      combT[(eo + 1) * 72 + en] = xh[1];
      combT[(eo + 2) * 72 + en] = xh[2];
      combT[(eo + 3) * 72 + en] = xh[3];
    }
    __syncthreads();

    // ---- P1b: build A into AmatPre2 (stride 72), diag exactly 1 ----
    {
      const int i = en, j0 = eo;
      float4 ad = *(const float4*)(adjG + i * N_ + j0);
      float4 rw = *(const float4*)(rarw + i * N_ + j0);
      float ri = rsS[i], mi = mS[i];
      float a0 = ad.x * (1.f - rw.x * fabsf(ri - rsS[j0 + 0])) * mi * mS[j0 + 0];
      float a1 = ad.y * (1.f - rw.y * fabsf(ri - rsS[j0 + 1])) * mi * mS[j0 + 1];
      float a2 = ad.z * (1.f - rw.z * fabsf(ri - rsS[j0 + 2])) * mi * mS[j0 + 2];
      float a3 = ad.w * (1.f - rw.w * fabsf(ri - rsS[j0 + 3])) * mi * mS[j0 + 3];
      if (i == j0 + 0) a0 = 1.f;
      if (i == j0 + 1) a1 = 1.f;
      if (i == j0 + 2) a2 = 1.f;
      if (i == j0 + 3) a3 = 1.f;
      f16x4 av = {(f16)a0, (f16)a1, (f16)a2, (f16)a3};
      *(f16x4*)(AmatPre2 + i * 72 + j0) = av;
    }
    __syncthreads();

    // ---- P2: msg = A @ comb (MFMA), 32 tiles over 16 waves; +rs GEMV ----
    {
#pragma unroll
      for (int s = 0; s < 2; ++s) {
        int tt = wv * 2 + s;
        int mt = tt >> 3, ft = tt & 7;
        f32x4 acc = {0.f, 0.f, 0.f, 0.f};
#pragma unroll
        for (int kt = 0; kt < 2; ++kt) {
          int j0 = 8 * lq + 32 * kt;
          f16x8 aF = *(const f16x8*)(AmatPre2 + (lm + 16 * mt) * 72 + j0);
          f16x8 bF = *(const f16x8*)(combT + (lm + 16 * ft) * 72 + j0);
          acc = __builtin_amdgcn_mfma_f32_16x16x32_f16(aF, bF, acc, 0, 0, 0);
        }
        int row = 16 * mt + 4 * lq;
        int col = 16 * ft + lm;
        actA[(row + 0) * 136 + col] = (f16)acc[0];
        actA[(row + 1) * 136 + col] = (f16)acc[1];
        actA[(row + 2) * 136 + col] = (f16)acc[2];
        actA[(row + 3) * 136 + col] = (f16)acc[3];
      }
      if (wv == 15) {  // msg_rs[n] = sum_j A[n,j]*rs[j]
        float s = 0.f;
        for (int j = 0; j < 64; j += 2) {
          f16x2 a2 = *(const f16x2*)(AmatPre2 + lane * 72 + j);
          s += (float)a2[0] * rsS[j] + (float)a2[1] * rsS[j + 1];
        }
        mrS[lane] = s;
      }
    }
    __syncthreads();

    // ---- P3: r,u gates (waves 0..7) + c-gate x-half (waves 8..11) ----
    f32x4 cacc[4];  // c-wave accumulators, live P3 -> P5
    if (wv < 8) {
      const int g = wv >> 2;   // 0=r -> pre1, 1=u -> AmatPre2
      const int nt = wv & 3;
      f32x4 acc[4] = {{0.f, 0.f, 0.f, 0.f}, {0.f, 0.f, 0.f, 0.f},
                      {0.f, 0.f, 0.f, 0.f}, {0.f, 0.f, 0.f, 0.f}};
      f16x8 qh[4];
#pragma unroll
      for (int mt = 0; mt < 4; ++mt)
        qh[mt] = *(const f16x8*)(qvS + (lm + 16 * mt) * 8);
#pragma unroll
      for (int kt = 0; kt < 4; ++kt) {
        f16x8 aF[4];
#pragma unroll
        for (int mt = 0; mt < 4; ++mt)
          aF[mt] = *(const f16x8*)(actA + (lm + 16 * mt) * 136 + 8 * lq + 32 * kt);
#pragma unroll
        for (int q = 0; q < 5; ++q) {
          f16x8 wF = *(const f16x8*)(Wpk +
              ((size_t)(((g * 5 + q) * 4 + kt) * 4 + nt) * 64 + lane) * 8);
#pragma unroll
          for (int mt = 0; mt < 4; ++mt) {
            f16x8 as = aF[mt] * qh[mt][q];
            acc[mt] = __builtin_amdgcn_mfma_f32_16x16x32_f16(as, wF, acc[mt], 0, 0, 0);
          }
        }
      }
      f16* dst = g ? AmatPre2 : pre1;
#pragma unroll
      for (int mt = 0; mt < 4; ++mt) {
        int row = 16 * mt + 4 * lq;
        int col = 16 * nt + lm;
        dst[(row + 0) * 68 + col] = (f16)acc[mt][0];
        dst[(row + 1) * 68 + col] = (f16)acc[mt][1];
        dst[(row + 2) * 68 + col] = (f16)acc[mt][2];
        dst[(row + 3) * 68 + col] = (f16)acc[mt][3];
      }
    } else if (wv < 12) {
      const int nt = wv - 8;
#pragma unroll
      for (int mt = 0; mt < 4; ++mt) cacc[mt] = f32x4{0.f, 0.f, 0.f, 0.f};
      f16x8 qh[4];
#pragma unroll
      for (int mt = 0; mt < 4; ++mt)
        qh[mt] = *(const f16x8*)(qvS + (lm + 16 * mt) * 8);
#pragma unroll
      for (int kt = 0; kt < 2; ++kt) {
        f16x8 aF[4];
#pragma unroll
        for (int mt = 0; mt < 4; ++mt)
          aF[mt] = *(const f16x8*)(xA + (lm + 16 * mt) * 72 + 8 * lq + 32 * kt);
#pragma unroll
        for (int q = 0; q < 5; ++q) {
          f16x8 wF = *(const f16x8*)(Wpk +
              ((size_t)(((2 * 5 + q) * 4 + kt) * 4 + nt) * 64 + lane) * 8);
#pragma unroll
          for (int mt = 0; mt < 4; ++mt) {
            f16x8 as = aF[mt] * qh[mt][q];
            cacc[mt] = __builtin_amdgcn_mfma_f32_16x16x32_f16(as, wF, cacc[mt], 0, 0, 0);
          }
        }
      }
    }
    __syncthreads();

    // ---- P4: elementwise r,u ; h_r -> regs + actA h-cols ----
    float uq[4], hrq[4];
    const bool upd = mS[en] > 0.f;
    {
      f16x4 pR = *(const f16x4*)(pre1 + en * 68 + eo);
      f16x4 pU = *(const f16x4*)(AmatPre2 + en * 68 + eo);
      float mr = mrS[en];
      f16x4 hrh;
#pragma unroll
      for (int k = 0; k < 4; ++k) {
        float preR = (float)pR[k] + mr * (float)wRp[k >> 1][k & 1] + (float)bRp[k >> 1][k & 1];
        float preU = (float)pU[k] + mr * (float)wUp[k >> 1][k & 1] + (float)bUp[k >> 1][k & 1];
        float r = 1.f / (1.f + expf(-preR));
        float u = 1.f / (1.f + expf(-preU));
        float hr = upd ? r * h[k] : h[k];
        uq[k] = u;
        hrq[k] = hr;
        hrh[k] = (f16)hr;
      }
      *(f16x4*)(actA + en * 136 + 64 + eo) = hrh;
    }
    __syncthreads();

    // ---- P5: c-gate h-half (waves 8..11), write preC to pre1 ----
    if (wv >= 8 && wv < 12) {
      const int nt = wv - 8;
      f16x8 qh[4];
#pragma unroll
      for (int mt = 0; mt < 4; ++mt)
        qh[mt] = *(const f16x8*)(qvS + (lm + 16 * mt) * 8);
#pragma unroll
      for (int kt = 2; kt < 4; ++kt) {
        f16x8 aF[4];
#pragma unroll
        for (int mt = 0; mt < 4; ++mt)
          aF[mt] = *(const f16x8*)(actA + (lm + 16 * mt) * 136 + 8 * lq + 32 * kt);
#pragma unroll
        for (int q = 0; q < 5; ++q) {
          f16x8 wF = *(const f16x8*)(Wpk +
              ((size_t)(((2 * 5 + q) * 4 + kt) * 4 + nt) * 64 + lane) * 8);
#pragma unroll
          for (int mt = 0; mt < 4; ++mt) {
            f16x8 as = aF[mt] * qh[mt][q];
            cacc[mt] = __builtin_amdgcn_mfma_f32_16x16x32_f16(as, wF, cacc[mt], 0, 0, 0);
          }
        }
      }
#pragma unroll
      for (int mt = 0; mt < 4; ++mt) {
        int row = 16 * mt + 4 * lq;
        int col = 16 * nt + lm;
        pre1[(row + 0) * 68 + col] = (f16)cacc[mt][0];
        pre1[(row + 1) * 68 + col] = (f16)cacc[mt][1];
        pre1[(row + 2) * 68 + col] = (f16)cacc[mt][2];
        pre1[(row + 3) * 68 + col] = (f16)cacc[mt][3];
      }
    }
    __syncthreads();

    // ---- P6: candidate + h update + combT h-rows + output ----
    {
      f16x4 pC = *(const f16x4*)(pre1 + en * 68 + eo);
      float rsv = rsS[en];
#pragma unroll
      for (int k = 0; k < 4; ++k) {
        float pc = (float)pC[k] + rsv * (float)wCp[k >> 1][k & 1] + (float)bCp[k >> 1][k & 1];
        float cand = tanhf(pc);
        float hn = upd ? (1.f - uq[k]) * hrq[k] + uq[k] * cand : h[k];
        h[k] = hn;
        combT[(64 + eo + k) * 72 + en] = (f16)hn;
      }
      if (t == lenm1) {
        float4 o4 = {h[0], h[1], h[2], h[3]};
        *(float4*)(out + ((size_t)b * N_ + en) * D_ + eo) = o4;
      }
    }
    __syncthreads();
  }
}

// ---------------------------------------------------------------------------
extern "C" void kernel_launch(void* const* d_in, const int* in_sizes, int n_in,
                              void* d_out, int out_size, void* d_ws, size_t ws_size,
                              hipStream_t stream) {
  const float* obs  = (const float*)d_in[0];
  const float* mask = (const float*)d_in[1];
  const int*   lens = (const int*)d_in[2];
  const float* ai   = (const float*)d_in[3];
  const float* vpr  = (const float*)d_in[4];
  const float* rarw = (const float*)d_in[5];
  const float* Wf1 = (const float*)d_in[6],  *bf1 = (const float*)d_in[7];
  const float* Wf2 = (const float*)d_in[8],  *bf2 = (const float*)d_in[9];
  const float* Wg1 = (const float*)d_in[10], *bg1 = (const float*)d_in[11];
  const float* Wg2 = (const float*)d_in[12], *bg2 = (const float*)d_in[13];
  const float* Wu = (const float*)d_in[14], *bu = (const float*)d_in[15];
  const float* Wr = (const float*)d_in[16], *br = (const float*)d_in[17];
  const float* Wc = (const float*)d_in[18], *bc = (const float*)d_in[19];

  char* p = (char*)d_ws;
  auto carve = [&](size_t bytes) {
    char* r = p;
    p += (bytes + 255) & ~(size_t)255;
    return r;
  };
  float* qv   = (float*)carve(N_ * Q_ * 4);
  float* neb  = (float*)carve(N_ * E_ * 4);
  float* adj  = (float*)carve(N_ * N_ * 4);
  float* brn  = (float*)carve(N_ * D_ * 4);
  float* bun  = (float*)carve(N_ * D_ * 4);
  float* bcn  = (float*)carve(N_ * D_ * 4);
  float* WrsR = (float*)carve(N_ * D_ * 4);
  float* WrsU = (float*)carve(N_ * D_ * 4);
  float* WrsC = (float*)carve(N_ * D_ * 4);
  float* vt   = (float*)carve(B_ * N_ * 4);
  f16* Wpk    = (f16*)carve((size_t)3 * 5 * 4 * 4 * 64 * 8 * 2);  // 245760 B

  k_mlps<<<N_, 256, 0, stream>>>(vpr, Wf1, bf1, Wf2, bf2, Wg1, bg1, Wg2, bg2, qv, neb);
  k_meta<<<N_, 64, 0, stream>>>(neb, qv, br, bu, bc, Wr, Wu, Wc,
                                adj, brn, bun, bcn, WrsR, WrsU, WrsC);
  k_pack<<<240, 64, 0, stream>>>(Wr, Wu, Wc, Wpk);
  k_vt<<<B_, 64, 0, stream>>>(mask, vt);
  k_seq<<<B_, 1024, 0, stream>>>(obs, mask, lens, ai, adj, rarw,
                                 brn, bun, bcn, WrsR, WrsU, WrsC,
                                 qv, vt, Wpk, (float*)d_out);
}